// Round 8
// baseline (265.514 us; speedup 1.0000x reference)
//
#include <hip/hip_runtime.h>
#include <stdint.h>

typedef unsigned int uint;
typedef unsigned short ushort;
typedef __attribute__((ext_vector_type(8))) short short8;
typedef __attribute__((ext_vector_type(16))) float floatx16;

// ---------- helpers ----------
__device__ inline ushort f2b(float f) {           // fp32 -> bf16 RNE
  union { float f; uint u; } c; c.f = f;
  uint u = c.u;
  u = (u + 0x7fffu + ((u >> 16) & 1u)) >> 16;
  return (ushort)u;
}
__device__ inline float b2f(ushort u) {
  union { uint i; float f; } c; c.i = ((uint)u) << 16; return c.f;
}

__device__ inline void gl_lds16(const ushort* g, ushort* l) {
  // async global->LDS, 16B/lane; LDS dest = wave-uniform base + lane*16
  __builtin_amdgcn_global_load_lds(
      (const __attribute__((address_space(1))) void*)g,
      (__attribute__((address_space(3))) void*)l, 16, 0, 0);
}

// ---------------------------------------------------------------------------
// One-shot fp32->bf16 convert: x (8M elems) + Wq/Wk/Wv (1M each).
// ---------------------------------------------------------------------------
__global__ __launch_bounds__(256) void cvt_all(
    const float* __restrict__ x,  const float* __restrict__ wq,
    const float* __restrict__ wk, const float* __restrict__ wv,
    ushort* __restrict__ xb, ushort* __restrict__ wb)
{
  const int b = blockIdx.x;
  const float* s; ushort* d; int i;
  if (b < 4096) {
    s = x; d = xb; i = b * 256 + threadIdx.x;
  } else {
    int t = b - 4096;
    int wsel = t >> 9;
    s = (wsel == 0) ? wq : (wsel == 1) ? wk : wv;
    d = wb + (size_t)wsel * (1024u * 1024u);
    i = (t & 511) * 256 + threadIdx.x;
  }
  float4 a = ((const float4*)s)[i * 2];
  float4 c = ((const float4*)s)[i * 2 + 1];
  short8 v;
  v[0] = (short)f2b(a.x); v[1] = (short)f2b(a.y);
  v[2] = (short)f2b(a.z); v[3] = (short)f2b(a.w);
  v[4] = (short)f2b(c.x); v[5] = (short)f2b(c.y);
  v[6] = (short)f2b(c.z); v[7] = (short)f2b(c.w);
  ((short8*)d)[i] = v;
}

// ---------------------------------------------------------------------------
// Shared GEMM-BT core:  C[m][n] = f( sum_k A[m][k] * B[n][k] )
// 128 x BN block tile (BN = 128 or 64), BK=64, 256 thr = 2x2 waves,
// MFMA 32x32x16 (floatx16 acc), global_load_lds width-16 staging into
// XOR-swizzled [rows][64] LDS tiles (chunk' = chunk ^ ((r^(r>>3))&7)) —
// kills all LDS bank conflicts (R5: 6.3M -> 0). No XCD swizzle (R6 regressed).
// MODE 0 (BN=128): fused-QKV split (n<2048 -> Q/K bf16 row-major, else Vt^T)
// MODE 1 (BN=128): p = exp2(s*scale) bf16 out; row sums atomically into Lsum
//                  (no max subtraction: |s|*scale bounded ~8, fp32-safe)
// MODE 2 (BN=64):  fp32 out, multiplied by 1/Lsum[row]
// ---------------------------------------------------------------------------
template <int MODE, int BN>
__device__ __forceinline__ void gemm_core(
    const ushort* __restrict__ A, int lda, size_t sA,
    const ushort* __restrict__ B, int ldb, size_t sB,
    void* __restrict__ C, int ldc, size_t sC,
    int K, float scale, float* __restrict__ Lsum)
{
  constexpr int NJ = BN / 64;          // n-frags per wave (2 or 1)
  constexpr int NB = BN / 32;          // 32-row staging groups for B (4 or 2)
  __shared__ ushort As[128 * 64];
  __shared__ ushort Bs[BN * 64];

  const int tid = threadIdx.x;
  const int bz  = blockIdx.z;
  A += (size_t)bz * sA;
  B += (size_t)bz * sB;

  const int m0 = blockIdx.y * 128;
  const int n0 = blockIdx.x * BN;

  const int lane = tid & 63;
  const int w    = tid >> 6;
  const int l32  = lane & 31;
  const int lh   = lane >> 5;          // 0/1 -> k-half of the 16-k step
  const int mw   = w >> 1;
  const int nw   = w & 1;

  // ---- staging pointers (32 rows per group; 8 lanes per 128B row) ----
  const int srow = tid >> 3;
  const ushort* agp[4];
  const ushort* bgp[NB];
#pragma unroll
  for (int c4 = 0; c4 < 4; ++c4) {
    int r   = c4 * 32 + srow;
    int col = (((tid & 7) ^ ((r ^ (r >> 3)) & 7))) * 8;
    agp[c4] = A + (size_t)(m0 + r) * lda + col;
  }
#pragma unroll
  for (int cb = 0; cb < NB; ++cb) {
    int r   = cb * 32 + srow;
    int col = (((tid & 7) ^ ((r ^ (r >> 3)) & 7))) * 8;
    bgp[cb] = B + (size_t)(n0 + r) * ldb + col;
  }

  // ---- fragment rows + swizzle keys (loop-invariant) ----
  int arow[2], aswz[2], brow[NJ], bswz[NJ];
#pragma unroll
  for (int t = 0; t < 2; ++t) {
    arow[t] = mw * 64 + t * 32 + l32;
    aswz[t] = (arow[t] ^ (arow[t] >> 3)) & 7;
  }
#pragma unroll
  for (int t = 0; t < NJ; ++t) {
    brow[t] = nw * (BN / 2) + t * 32 + l32;
    bswz[t] = (brow[t] ^ (brow[t] >> 3)) & 7;
  }

  floatx16 acc[2][NJ];
#pragma unroll
  for (int i = 0; i < 2; ++i)
#pragma unroll
    for (int j = 0; j < NJ; ++j)
#pragma unroll
      for (int r = 0; r < 16; ++r) acc[i][j][r] = 0.f;

  for (int k0 = 0; k0 < K; k0 += 64) {
    __syncthreads();
#pragma unroll
    for (int c4 = 0; c4 < 4; ++c4) {
      gl_lds16(agp[c4], &As[(c4 * 32 + w * 8) * 64]);
      agp[c4] += 64;
    }
#pragma unroll
    for (int cb = 0; cb < NB; ++cb) {
      gl_lds16(bgp[cb], &Bs[(cb * 32 + w * 8) * 64]);
      bgp[cb] += 64;
    }
    __syncthreads();

#pragma unroll
    for (int s = 0; s < 4; ++s) {        // 4 k-steps of 16
      short8 af[2], bf[NJ];
#pragma unroll
      for (int t = 0; t < 2; ++t)
        af[t] = *(const short8*)&As[arow[t] * 64 + (((s * 2 + lh) ^ aswz[t]) * 8)];
#pragma unroll
      for (int t = 0; t < NJ; ++t)
        bf[t] = *(const short8*)&Bs[brow[t] * 64 + (((s * 2 + lh) ^ bswz[t]) * 8)];
#pragma unroll
      for (int i = 0; i < 2; ++i)
#pragma unroll
        for (int j = 0; j < NJ; ++j)
          acc[i][j] = __builtin_amdgcn_mfma_f32_32x32x16_bf16(
              af[i], bf[j], acc[i][j], 0, 0, 0);
    }
  }

  // ---- epilogue; C/D (32x32): col = lane&31, row = (reg&3)+8*(reg>>2)+4*lh
  if (MODE == 0) {            // fused-QKV split
#pragma unroll
    for (int i = 0; i < 2; ++i)
#pragma unroll
      for (int j = 0; j < NJ; ++j) {
        const int mbase = m0 + mw * 64 + i * 32 + 4 * lh;
        const int ng    = n0 + nw * (BN / 2) + j * 32 + l32;
        if (ng < 2048) {
          ushort* dst = (ushort*)C + (size_t)(ng >> 10) * (8192u * 1024u);
          const int nn = ng & 1023;
#pragma unroll
          for (int g = 0; g < 4; ++g)
#pragma unroll
            for (int r = 0; r < 4; ++r)
              dst[(size_t)(mbase + 8 * g + r) * 1024 + nn] =
                  f2b(acc[i][j][4 * g + r]);
        } else {
          ushort* Vo = (ushort*)C + (size_t)2 * 8192 * 1024;
#pragma unroll
          for (int g = 0; g < 4; ++g) {
            uint lo = (uint)f2b(acc[i][j][4 * g + 0]) |
                      ((uint)f2b(acc[i][j][4 * g + 1]) << 16);
            uint hi = (uint)f2b(acc[i][j][4 * g + 2]) |
                      ((uint)f2b(acc[i][j][4 * g + 3]) << 16);
            *(uint2*)&Vo[(size_t)(ng - 2048) * 8192 + mbase + 8 * g] =
                make_uint2(lo, hi);
          }
        }
      }
  } else if (MODE == 1) {     // p = exp2(s*scale), accumulate row sums
    ushort* Cb = (ushort*)C + (size_t)bz * sC;
    float* Lb = Lsum + (size_t)bz * 2048;
    const int ng0 = n0 + nw * (BN / 2) + l32;
#pragma unroll
    for (int i = 0; i < 2; ++i) {
      const int mbase = m0 + mw * 64 + i * 32 + 4 * lh;
#pragma unroll
      for (int g = 0; g < 4; ++g)
#pragma unroll
        for (int r = 0; r < 4; ++r) {
          const int mg = mbase + 8 * g + r;
          float p0 = exp2f(acc[i][0][4 * g + r] * scale);
          float p1 = exp2f(acc[i][1][4 * g + r] * scale);
          ushort u0 = f2b(p0), u1 = f2b(p1);
          Cb[(size_t)mg * ldc + ng0]      = u0;
          Cb[(size_t)mg * ldc + ng0 + 32] = u1;
          float ps = b2f(u0) + b2f(u1);   // sum of *rounded* p (matches PV)
#pragma unroll
          for (int d = 1; d < 32; d <<= 1) ps += __shfl_xor(ps, d);
          if (l32 == 0) atomicAdd(&Lb[mg], ps);
        }
    }
  } else {                    // MODE 2: normalized fp32 output (BN=64, NJ=1)
    float* Cb = (float*)C + (size_t)bz * sC;
    const float* Lb = Lsum + (size_t)bz * 2048;
    const int ng = n0 + nw * (BN / 2) + l32;
#pragma unroll
    for (int i = 0; i < 2; ++i) {
      const int mbase = m0 + mw * 64 + i * 32 + 4 * lh;
#pragma unroll
      for (int g = 0; g < 4; ++g)
#pragma unroll
        for (int r = 0; r < 4; ++r) {
          const int mg = mbase + 8 * g + r;
          const float inv = 1.0f / Lb[mg];
          Cb[(size_t)mg * ldc + ng] = acc[i][0][4 * g + r] * inv;
        }
    }
  }
}

// ---- distinct symbols per stage (counter attribution) ----
__global__ __launch_bounds__(256, 3) void gemm_qkv(
    const ushort* __restrict__ A, int lda, size_t sA,
    const ushort* __restrict__ B, int ldb, size_t sB,
    void* __restrict__ C, int ldc, size_t sC, int K, float scale,
    float* __restrict__ Lsum) {
  gemm_core<0, 128>(A, lda, sA, B, ldb, sB, C, ldc, sC, K, scale, Lsum);
}
__global__ __launch_bounds__(256, 4) void gemm_s(
    const ushort* __restrict__ A, int lda, size_t sA,
    const ushort* __restrict__ B, int ldb, size_t sB,
    void* __restrict__ C, int ldc, size_t sC, int K, float scale,
    float* __restrict__ Lsum) {
  gemm_core<1, 128>(A, lda, sA, B, ldb, sB, C, ldc, sC, K, scale, Lsum);
}
__global__ __launch_bounds__(256, 4) void gemm_pv(
    const ushort* __restrict__ A, int lda, size_t sA,
    const ushort* __restrict__ B, int ldb, size_t sB,
    void* __restrict__ C, int ldc, size_t sC, int K, float scale,
    float* __restrict__ Lsum) {
  gemm_core<2, 64>(A, lda, sA, B, ldb, sB, C, ldc, sC, K, scale, Lsum);
}

// ---------------------------------------------------------------------------
extern "C" void kernel_launch(void* const* d_in, const int* in_sizes, int n_in,
                              void* d_out, int out_size, void* d_ws, size_t ws_size,
                              hipStream_t stream) {
  const float* x  = (const float*)d_in[0];
  const float* Wq = (const float*)d_in[1];
  const float* Wk = (const float*)d_in[2];
  const float* Wv = (const float*)d_in[3];
  float* outp = (float*)d_out;

  const float SCALE = 1.4426950408889634f / 32.0f;   // log2(e)/sqrt(1024)

  // ws layout (bf16): xb[8192][1024] | Wb[3072][1024] | Qb | Kb | Vt[1024][8192]
  //                   | Lsum fp32 [4][2048] | S bf16
  ushort* xb = (ushort*)d_ws;
  ushort* Wb = xb + (size_t)8192 * 1024;
  ushort* Qb = Wb + (size_t)3 * 1024 * 1024;
  ushort* Kb = Qb + (size_t)8192 * 1024;
  ushort* Vt = Kb + (size_t)8192 * 1024;
  float*  Ls = (float*)(Vt + (size_t)8192 * 1024);
  ushort* Sb = (ushort*)(Ls + 4 * 2048);

  const size_t NEED_FULL = 106987520;   // ... + S bf16 [4][2048][2048]

  cvt_all<<<5632, 256, 0, stream>>>(x, Wq, Wk, Wv, xb, Wb);

  // fused QKV projection: [8192x1024] x [3072x1024]^T, split epilogue
  gemm_qkv<<<dim3(24, 64, 1), 256, 0, stream>>>(
      xb, 1024, 0, Wb, 1024, 0, Qb, 0, 0, 1024, 1.f, nullptr);

  if (ws_size >= NEED_FULL) {
    hipMemsetAsync(Ls, 0, 4 * 2048 * sizeof(float), stream);
    gemm_s<<<dim3(16, 16, 4), 256, 0, stream>>>(
        Qb, 1024, (size_t)2048 * 1024, Kb, 1024, (size_t)2048 * 1024,
        Sb, 2048, (size_t)2048 * 2048, 1024, SCALE, Ls);
    gemm_pv<<<dim3(16, 16, 4), 256, 0, stream>>>(
        Sb, 2048, (size_t)2048 * 2048, Vt, 8192, 2048,
        outp, 1024, (size_t)2048 * 1024, 2048, 1.f, Ls);
  } else {
    // per-batch S buffer
    for (int b = 0; b < 4; ++b) {
      hipMemsetAsync(Ls, 0, 2048 * sizeof(float), stream);
      gemm_s<<<dim3(16, 16, 1), 256, 0, stream>>>(
          Qb + (size_t)b * 2048 * 1024, 1024, 0,
          Kb + (size_t)b * 2048 * 1024, 1024, 0,
          Sb, 2048, 0, 1024, SCALE, Ls);
      gemm_pv<<<dim3(16, 16, 1), 256, 0, stream>>>(
          Sb, 2048, 0, Vt + (size_t)b * 2048, 8192, 0,
          outp + (size_t)b * 2048 * 1024, 1024, 0, 2048, 1.f, Ls);
    }
  }
}

// Round 10
// 262.950 us; speedup vs baseline: 1.0098x; 1.0098x over previous
//
#include <hip/hip_runtime.h>
#include <stdint.h>

typedef unsigned int uint;
typedef unsigned short ushort;
typedef __attribute__((ext_vector_type(8))) short short8;
typedef __attribute__((ext_vector_type(16))) float floatx16;

#define MEG (1024u * 1024u)

// ---------- helpers ----------
__device__ inline ushort f2b(float f) {           // fp32 -> bf16 RNE
  union { float f; uint u; } c; c.f = f;
  uint u = c.u;
  u = (u + 0x7fffu + ((u >> 16) & 1u)) >> 16;
  return (ushort)u;
}
__device__ inline float b2f(ushort u) {
  union { uint i; float f; } c; c.i = ((uint)u) << 16; return c.f;
}

__device__ inline void gl_lds16(const ushort* g, ushort* l) {
  // async global->LDS, 16B/lane; LDS dest = wave-uniform base + lane*16
  __builtin_amdgcn_global_load_lds(
      (const __attribute__((address_space(1))) void*)g,
      (__attribute__((address_space(3))) void*)l, 16, 0, 0);
}

// ---------------------------------------------------------------------------
// fp32->bf16 convert (x: 4096 blocks, W: 3x512 blocks) + Ls zeroing (1 block).
// ---------------------------------------------------------------------------
__global__ __launch_bounds__(256) void cvt_all(
    const float* __restrict__ x,  const float* __restrict__ wq,
    const float* __restrict__ wk, const float* __restrict__ wv,
    ushort* __restrict__ xb, ushort* __restrict__ wb,
    float* __restrict__ ls)
{
  const int b = blockIdx.x;
  if (b >= 5632) {                      // zero Lsum[4][2048]
    float4 z = make_float4(0.f, 0.f, 0.f, 0.f);
#pragma unroll
    for (int j = 0; j < 8; ++j)
      ((float4*)ls)[threadIdx.x * 8 + j] = z;
    return;
  }
  const float* s; ushort* d; int i;
  if (b < 4096) {
    s = x; d = xb; i = b * 256 + threadIdx.x;
  } else {
    int t = b - 4096;
    int wsel = t >> 9;
    s = (wsel == 0) ? wq : (wsel == 1) ? wk : wv;
    d = wb + (size_t)wsel * MEG;
    i = (t & 511) * 256 + threadIdx.x;
  }
  float4 a = ((const float4*)s)[i * 2];
  float4 c = ((const float4*)s)[i * 2 + 1];
  short8 v;
  v[0] = (short)f2b(a.x); v[1] = (short)f2b(a.y);
  v[2] = (short)f2b(a.z); v[3] = (short)f2b(a.w);
  v[4] = (short)f2b(c.x); v[5] = (short)f2b(c.y);
  v[6] = (short)f2b(c.z); v[7] = (short)f2b(c.w);
  ((short8*)d)[i] = v;
}

// ---------------------------------------------------------------------------
// Shared GEMM-BT core:  C[m][n] = f( sum_k A[m][k] * B[n][k] )
// 128 x BN block tile (BN = 128 or 64), BK=64, 256 thr = 2x2 waves,
// MFMA 32x32x16 (floatx16 acc), global_load_lds width-16 staging into
// XOR-swizzled [rows][64] LDS tiles (chunk' = chunk ^ ((r^(r>>3))&7)) —
// kills all LDS bank conflicts (R5: 6.3M -> 0). No XCD swizzle (R6 regressed).
// MODE 0 (BN=128): fused-QKV split (n<2048 -> Q/K bf16 row-major, else Vt^T)
// MODE 1 (BN=128): p = exp2(s*scale) bf16 out; row sums atomically into Lsum
//                  (no max subtraction: |s|*scale bounded ~8, fp32-safe)
// MODE 2 (BN=64):  fp32 out, multiplied by 1/Lsum[row]
// ---------------------------------------------------------------------------
template <int MODE, int BN>
__device__ __forceinline__ void gemm_core(
    const ushort* __restrict__ A, int lda, size_t sA,
    const ushort* __restrict__ B, int ldb, size_t sB,
    void* __restrict__ C, int ldc, size_t sC,
    int K, float scale, float* __restrict__ Lsum)
{
  constexpr int NJ = BN / 64;          // n-frags per wave (2 or 1)
  constexpr int NB = BN / 32;          // 32-row staging groups for B (4 or 2)
  __shared__ ushort As[128 * 64];
  __shared__ ushort Bs[BN * 64];

  const int tid = threadIdx.x;
  const int bz  = blockIdx.z;
  A += (size_t)bz * sA;
  B += (size_t)bz * sB;

  const int m0 = blockIdx.y * 128;
  const int n0 = blockIdx.x * BN;

  const int lane = tid & 63;
  const int w    = tid >> 6;
  const int l32  = lane & 31;
  const int lh   = lane >> 5;          // 0/1 -> k-half of the 16-k step
  const int mw   = w >> 1;
  const int nw   = w & 1;

  // ---- staging pointers (32 rows per group; 8 lanes per 128B row) ----
  const int srow = tid >> 3;
  const ushort* agp[4];
  const ushort* bgp[NB];
#pragma unroll
  for (int c4 = 0; c4 < 4; ++c4) {
    int r   = c4 * 32 + srow;
    int col = (((tid & 7) ^ ((r ^ (r >> 3)) & 7))) * 8;
    agp[c4] = A + (size_t)(m0 + r) * lda + col;
  }
#pragma unroll
  for (int cb = 0; cb < NB; ++cb) {
    int r   = cb * 32 + srow;
    int col = (((tid & 7) ^ ((r ^ (r >> 3)) & 7))) * 8;
    bgp[cb] = B + (size_t)(n0 + r) * ldb + col;
  }

  // ---- fragment rows + swizzle keys (loop-invariant) ----
  int arow[2], aswz[2], brow[NJ], bswz[NJ];
#pragma unroll
  for (int t = 0; t < 2; ++t) {
    arow[t] = mw * 64 + t * 32 + l32;
    aswz[t] = (arow[t] ^ (arow[t] >> 3)) & 7;
  }
#pragma unroll
  for (int t = 0; t < NJ; ++t) {
    brow[t] = nw * (BN / 2) + t * 32 + l32;
    bswz[t] = (brow[t] ^ (brow[t] >> 3)) & 7;
  }

  floatx16 acc[2][NJ];
#pragma unroll
  for (int i = 0; i < 2; ++i)
#pragma unroll
    for (int j = 0; j < NJ; ++j)
#pragma unroll
      for (int r = 0; r < 16; ++r) acc[i][j][r] = 0.f;

  for (int k0 = 0; k0 < K; k0 += 64) {
    __syncthreads();
#pragma unroll
    for (int c4 = 0; c4 < 4; ++c4) {
      gl_lds16(agp[c4], &As[(c4 * 32 + w * 8) * 64]);
      agp[c4] += 64;
    }
#pragma unroll
    for (int cb = 0; cb < NB; ++cb) {
      gl_lds16(bgp[cb], &Bs[(cb * 32 + w * 8) * 64]);
      bgp[cb] += 64;
    }
    __syncthreads();

#pragma unroll
    for (int s = 0; s < 4; ++s) {        // 4 k-steps of 16
      short8 af[2], bf[NJ];
#pragma unroll
      for (int t = 0; t < 2; ++t)
        af[t] = *(const short8*)&As[arow[t] * 64 + (((s * 2 + lh) ^ aswz[t]) * 8)];
#pragma unroll
      for (int t = 0; t < NJ; ++t)
        bf[t] = *(const short8*)&Bs[brow[t] * 64 + (((s * 2 + lh) ^ bswz[t]) * 8)];
#pragma unroll
      for (int i = 0; i < 2; ++i)
#pragma unroll
        for (int j = 0; j < NJ; ++j)
          acc[i][j] = __builtin_amdgcn_mfma_f32_32x32x16_bf16(
              af[i], bf[j], acc[i][j], 0, 0, 0);
    }
  }

  // ---- epilogue; C/D (32x32): col = lane&31, row = (reg&3)+8*(reg>>2)+4*lh
  if constexpr (MODE == 0) {   // fused-QKV split
#pragma unroll
    for (int i = 0; i < 2; ++i)
#pragma unroll
      for (int j = 0; j < NJ; ++j) {
        const int mbase = m0 + mw * 64 + i * 32 + 4 * lh;
        const int ng    = n0 + nw * (BN / 2) + j * 32 + l32;
        if (ng < 2048) {
          // Qb @ C, Kb @ C + 8M elems
          ushort* dst = (ushort*)C + (size_t)(ng >> 10) * (8u * MEG);
          const int nn = ng & 1023;
#pragma unroll
          for (int g = 0; g < 4; ++g)
#pragma unroll
            for (int r = 0; r < 4; ++r)
              dst[(size_t)(mbase + 8 * g + r) * 1024 + nn] =
                  f2b(acc[i][j][4 * g + r]);
        } else {
          // Vt @ C + 16M elems, transposed [1024][8192]
          ushort* Vo = (ushort*)C + (size_t)16 * MEG;
#pragma unroll
          for (int g = 0; g < 4; ++g) {
            uint lo = (uint)f2b(acc[i][j][4 * g + 0]) |
                      ((uint)f2b(acc[i][j][4 * g + 1]) << 16);
            uint hi = (uint)f2b(acc[i][j][4 * g + 2]) |
                      ((uint)f2b(acc[i][j][4 * g + 3]) << 16);
            *(uint2*)&Vo[(size_t)(ng - 2048) * 8192 + mbase + 8 * g] =
                make_uint2(lo, hi);
          }
        }
      }
  } else if constexpr (MODE == 1) {   // p = exp2(s*scale), row sums -> Lsum
    ushort* Cb = (ushort*)C + (size_t)bz * sC;
    float* Lb = Lsum + (size_t)bz * 2048;
    const int ng0 = n0 + nw * (BN / 2) + l32;
#pragma unroll
    for (int i = 0; i < 2; ++i) {
      const int mbase = m0 + mw * 64 + i * 32 + 4 * lh;
#pragma unroll
      for (int g = 0; g < 4; ++g)
#pragma unroll
        for (int r = 0; r < 4; ++r) {
          const int mg = mbase + 8 * g + r;
          float p0 = exp2f(acc[i][0][4 * g + r] * scale);
          float p1 = exp2f(acc[i][NJ - 1][4 * g + r] * scale);
          ushort u0 = f2b(p0), u1 = f2b(p1);
          Cb[(size_t)mg * ldc + ng0]      = u0;
          Cb[(size_t)mg * ldc + ng0 + 32] = u1;
          float ps = b2f(u0) + b2f(u1);   // sum of *rounded* p (matches PV)
#pragma unroll
          for (int d = 1; d < 32; d <<= 1) ps += __shfl_xor(ps, d);
          if (l32 == 0) atomicAdd(&Lb[mg], ps);
        }
    }
  } else {                    // MODE 2: normalized fp32 output (BN=64, NJ=1)
    float* Cb = (float*)C + (size_t)bz * sC;
    const float* Lb = Lsum + (size_t)bz * 2048;
    const int ng = n0 + nw * (BN / 2) + l32;
#pragma unroll
    for (int i = 0; i < 2; ++i) {
      const int mbase = m0 + mw * 64 + i * 32 + 4 * lh;
#pragma unroll
      for (int g = 0; g < 4; ++g)
#pragma unroll
        for (int r = 0; r < 4; ++r) {
          const int mg = mbase + 8 * g + r;
          const float inv = 1.0f / Lb[mg];
          Cb[(size_t)mg * ldc + ng] = acc[i][0][4 * g + r] * inv;
        }
    }
  }
}

// ---- distinct symbols per stage (counter attribution) ----
__global__ __launch_bounds__(256, 3) void gemm_qkv(
    const ushort* __restrict__ A, int lda, size_t sA,
    const ushort* __restrict__ B, int ldb, size_t sB,
    void* __restrict__ C, int ldc, size_t sC, int K, float scale,
    float* __restrict__ Lsum) {
  gemm_core<0, 128>(A, lda, sA, B, ldb, sB, C, ldc, sC, K, scale, Lsum);
}
__global__ __launch_bounds__(256, 3) void gemm_s(
    const ushort* __restrict__ A, int lda, size_t sA,
    const ushort* __restrict__ B, int ldb, size_t sB,
    void* __restrict__ C, int ldc, size_t sC, int K, float scale,
    float* __restrict__ Lsum) {
  gemm_core<1, 128>(A, lda, sA, B, ldb, sB, C, ldc, sC, K, scale, Lsum);
}
__global__ __launch_bounds__(256, 4) void gemm_pv(
    const ushort* __restrict__ A, int lda, size_t sA,
    const ushort* __restrict__ B, int ldb, size_t sB,
    void* __restrict__ C, int ldc, size_t sC, int K, float scale,
    float* __restrict__ Lsum) {
  gemm_core<2, 64>(A, lda, sA, B, ldb, sB, C, ldc, sC, K, scale, Lsum);
}

// ---------------------------------------------------------------------------
// ws layout (ushort elems), total 80 MiB + 32 KiB  (proven ws >= 90.2 MB):
//   Qb @ 0      [8192][1024]   (16 MiB)
//   Kb @ 8M     [8192][1024]   (16 MiB)
//   Vt @ 16M    [1024][8192]   (16 MiB)
//   xb @ 24M    [8192][1024]   (16 MiB)  -- dead after QKV
//   Wb @ 32M    [3072][1024]   ( 6 MiB)  -- dead after QKV
//   P  @ 24M    [4][2048][2048] (32 MiB) -- OVERLAYS xb+Wb (both dead)
//   Ls @ 40M    fp32 [4][2048]  (32 KiB)
// ---------------------------------------------------------------------------
extern "C" void kernel_launch(void* const* d_in, const int* in_sizes, int n_in,
                              void* d_out, int out_size, void* d_ws, size_t ws_size,
                              hipStream_t stream) {
  const float* x  = (const float*)d_in[0];
  const float* Wq = (const float*)d_in[1];
  const float* Wk = (const float*)d_in[2];
  const float* Wv = (const float*)d_in[3];
  float* outp = (float*)d_out;

  const float SCALE = 1.4426950408889634f / 32.0f;   // log2(e)/sqrt(1024)

  ushort* W0 = (ushort*)d_ws;
  ushort* Qb = W0;
  ushort* Kb = W0 + (size_t)8 * MEG;
  ushort* Vt = W0 + (size_t)16 * MEG;
  ushort* xb = W0 + (size_t)24 * MEG;
  ushort* Wb = W0 + (size_t)32 * MEG;
  ushort* Pb = W0 + (size_t)24 * MEG;            // overlays xb/Wb after QKV

  const size_t NEED_FULL = ((size_t)40 * MEG) * 2 + 4 * 2048 * 4;  // 83,918,848
  const bool full = ws_size >= NEED_FULL;
  float* Ls = full ? (float*)(W0 + (size_t)40 * MEG)
                   : (float*)(W0 + (size_t)28 * MEG);  // per-batch: P is 8 MiB

  cvt_all<<<5633, 256, 0, stream>>>(x, Wq, Wk, Wv, xb, Wb, Ls);

  // fused QKV projection: [8192x1024] x [3072x1024]^T, split epilogue
  gemm_qkv<<<dim3(24, 64, 1), 256, 0, stream>>>(
      xb, 1024, 0, Wb, 1024, 0, Qb, 1024, 0, 1024, 1.f, nullptr);

  if (full) {
    gemm_s<<<dim3(16, 16, 4), 256, 0, stream>>>(
        Qb, 1024, (size_t)2048 * 1024, Kb, 1024, (size_t)2048 * 1024,
        Pb, 2048, (size_t)2048 * 2048, 1024, SCALE, Ls);
    gemm_pv<<<dim3(16, 16, 4), 256, 0, stream>>>(
        Pb, 2048, (size_t)2048 * 2048, Vt, 8192, 2048,
        outp, 1024, (size_t)2048 * 1024, 2048, 1.f, Ls);
  } else {
    // per-batch fallback (P single batch @24M, Ls @28M)
    for (int b = 0; b < 4; ++b) {
      (void)hipMemsetAsync(Ls, 0, 2048 * sizeof(float), stream);
      gemm_s<<<dim3(16, 16, 1), 256, 0, stream>>>(
          Qb + (size_t)b * 2048 * 1024, 1024, 0,
          Kb + (size_t)b * 2048 * 1024, 1024, 0,
          Pb, 2048, 0, 1024, SCALE, Ls);
      gemm_pv<<<dim3(16, 16, 1), 256, 0, stream>>>(
          Pb, 2048, 0, Vt + (size_t)b * 2048, 8192, 0,
          outp + (size_t)b * 2048 * 1024, 1024, 0, 2048, 1.f, Ls);
    }
  }
}

// Round 11
// 250.589 us; speedup vs baseline: 1.0596x; 1.0493x over previous
//
#include <hip/hip_runtime.h>
#include <stdint.h>

typedef unsigned int uint;
typedef unsigned short ushort;
typedef __attribute__((ext_vector_type(8))) short short8;
typedef __attribute__((ext_vector_type(16))) float floatx16;

#define MEG (1024u * 1024u)

// ---------- helpers ----------
__device__ inline ushort f2b(float f) {           // fp32 -> bf16 RNE
  union { float f; uint u; } c; c.f = f;
  uint u = c.u;
  u = (u + 0x7fffu + ((u >> 16) & 1u)) >> 16;
  return (ushort)u;
}
__device__ inline float b2f(ushort u) {
  union { uint i; float f; } c; c.i = ((uint)u) << 16; return c.f;
}

__device__ inline void gl_lds16(const ushort* g, ushort* l) {
  // async global->LDS, 16B/lane; LDS dest = wave-uniform base + lane*16
  __builtin_amdgcn_global_load_lds(
      (const __attribute__((address_space(1))) void*)g,
      (__attribute__((address_space(3))) void*)l, 16, 0, 0);
}

// ---------------------------------------------------------------------------
// fp32->bf16 convert (x: 4096 blocks, W: 3x512 blocks) + Ls zeroing (1 block).
// ---------------------------------------------------------------------------
__global__ __launch_bounds__(256) void cvt_all(
    const float* __restrict__ x,  const float* __restrict__ wq,
    const float* __restrict__ wk, const float* __restrict__ wv,
    ushort* __restrict__ xb, ushort* __restrict__ wb,
    float* __restrict__ ls)
{
  const int b = blockIdx.x;
  if (b >= 5632) {                      // zero Lsum[4][2048]
    float4 z = make_float4(0.f, 0.f, 0.f, 0.f);
#pragma unroll
    for (int j = 0; j < 8; ++j)
      ((float4*)ls)[threadIdx.x * 8 + j] = z;
    return;
  }
  const float* s; ushort* d; int i;
  if (b < 4096) {
    s = x; d = xb; i = b * 256 + threadIdx.x;
  } else {
    int t = b - 4096;
    int wsel = t >> 9;
    s = (wsel == 0) ? wq : (wsel == 1) ? wk : wv;
    d = wb + (size_t)wsel * MEG;
    i = (t & 511) * 256 + threadIdx.x;
  }
  float4 a = ((const float4*)s)[i * 2];
  float4 c = ((const float4*)s)[i * 2 + 1];
  short8 v;
  v[0] = (short)f2b(a.x); v[1] = (short)f2b(a.y);
  v[2] = (short)f2b(a.z); v[3] = (short)f2b(a.w);
  v[4] = (short)f2b(c.x); v[5] = (short)f2b(c.y);
  v[6] = (short)f2b(c.z); v[7] = (short)f2b(c.w);
  ((short8*)d)[i] = v;
}

// ---------------------------------------------------------------------------
// Shared GEMM-BT core:  C[m][n] = f( sum_k A[m][k] * B[n][k] )
// 128 x BN block tile (BN = 128 or 64), BK=64, 256 thr = 2x2 waves,
// MFMA 32x32x16 (floatx16 acc), global_load_lds width-16 staging into
// XOR-swizzled [rows][64] LDS tiles (chunk' = chunk ^ ((r^(r>>3))&7)) —
// kills all LDS bank conflicts (R5: 6.3M -> 0). No XCD swizzle (R6 regressed).
// MODE 0 (BN=128): fused-QKV split (n<2048 -> Q/K bf16 row-major, else Vt^T)
// MODE 1 (BN=128): p = exp2(s*scale) bf16 out; row sums atomically into Lsum
//                  (no max subtraction: |s|*scale bounded ~8, fp32-safe)
// MODE 2: fp32 out, multiplied by 1/Lsum[row]
// ---------------------------------------------------------------------------
template <int MODE, int BN>
__device__ __forceinline__ void gemm_core(
    const ushort* __restrict__ A, int lda, size_t sA,
    const ushort* __restrict__ B, int ldb, size_t sB,
    void* __restrict__ C, int ldc, size_t sC,
    int K, float scale, float* __restrict__ Lsum)
{
  constexpr int NJ = BN / 64;          // n-frags per wave (2 or 1)
  constexpr int NB = BN / 32;          // 32-row staging groups for B (4 or 2)
  __shared__ ushort As[128 * 64];
  __shared__ ushort Bs[BN * 64];

  const int tid = threadIdx.x;
  const int bz  = blockIdx.z;
  A += (size_t)bz * sA;
  B += (size_t)bz * sB;

  const int m0 = blockIdx.y * 128;
  const int n0 = blockIdx.x * BN;

  const int lane = tid & 63;
  const int w    = tid >> 6;
  const int l32  = lane & 31;
  const int lh   = lane >> 5;          // 0/1 -> k-half of the 16-k step
  const int mw   = w >> 1;
  const int nw   = w & 1;

  // ---- staging pointers (32 rows per group; 8 lanes per 128B row) ----
  const int srow = tid >> 3;
  const ushort* agp[4];
  const ushort* bgp[NB];
#pragma unroll
  for (int c4 = 0; c4 < 4; ++c4) {
    int r   = c4 * 32 + srow;
    int col = (((tid & 7) ^ ((r ^ (r >> 3)) & 7))) * 8;
    agp[c4] = A + (size_t)(m0 + r) * lda + col;
  }
#pragma unroll
  for (int cb = 0; cb < NB; ++cb) {
    int r   = cb * 32 + srow;
    int col = (((tid & 7) ^ ((r ^ (r >> 3)) & 7))) * 8;
    bgp[cb] = B + (size_t)(n0 + r) * ldb + col;
  }

  // ---- fragment rows + swizzle keys (loop-invariant) ----
  int arow[2], aswz[2], brow[NJ], bswz[NJ];
#pragma unroll
  for (int t = 0; t < 2; ++t) {
    arow[t] = mw * 64 + t * 32 + l32;
    aswz[t] = (arow[t] ^ (arow[t] >> 3)) & 7;
  }
#pragma unroll
  for (int t = 0; t < NJ; ++t) {
    brow[t] = nw * (BN / 2) + t * 32 + l32;
    bswz[t] = (brow[t] ^ (brow[t] >> 3)) & 7;
  }

  floatx16 acc[2][NJ];
#pragma unroll
  for (int i = 0; i < 2; ++i)
#pragma unroll
    for (int j = 0; j < NJ; ++j)
#pragma unroll
      for (int r = 0; r < 16; ++r) acc[i][j][r] = 0.f;

  for (int k0 = 0; k0 < K; k0 += 64) {
    __syncthreads();
#pragma unroll
    for (int c4 = 0; c4 < 4; ++c4) {
      gl_lds16(agp[c4], &As[(c4 * 32 + w * 8) * 64]);
      agp[c4] += 64;
    }
#pragma unroll
    for (int cb = 0; cb < NB; ++cb) {
      gl_lds16(bgp[cb], &Bs[(cb * 32 + w * 8) * 64]);
      bgp[cb] += 64;
    }
    __syncthreads();

#pragma unroll
    for (int s = 0; s < 4; ++s) {        // 4 k-steps of 16
      short8 af[2], bf[NJ];
#pragma unroll
      for (int t = 0; t < 2; ++t)
        af[t] = *(const short8*)&As[arow[t] * 64 + (((s * 2 + lh) ^ aswz[t]) * 8)];
#pragma unroll
      for (int t = 0; t < NJ; ++t)
        bf[t] = *(const short8*)&Bs[brow[t] * 64 + (((s * 2 + lh) ^ bswz[t]) * 8)];
#pragma unroll
      for (int i = 0; i < 2; ++i)
#pragma unroll
        for (int j = 0; j < NJ; ++j)
          acc[i][j] = __builtin_amdgcn_mfma_f32_32x32x16_bf16(
              af[i], bf[j], acc[i][j], 0, 0, 0);
    }
  }

  // ---- epilogue; C/D (32x32): col = lane&31, row = (reg&3)+8*(reg>>2)+4*lh
  if constexpr (MODE == 0) {   // fused-QKV split
#pragma unroll
    for (int i = 0; i < 2; ++i)
#pragma unroll
      for (int j = 0; j < NJ; ++j) {
        const int mbase = m0 + mw * 64 + i * 32 + 4 * lh;
        const int ng    = n0 + nw * (BN / 2) + j * 32 + l32;
        if (ng < 2048) {
          // Qb @ C, Kb @ C + 8M elems
          ushort* dst = (ushort*)C + (size_t)(ng >> 10) * (8u * MEG);
          const int nn = ng & 1023;
#pragma unroll
          for (int g = 0; g < 4; ++g)
#pragma unroll
            for (int r = 0; r < 4; ++r)
              dst[(size_t)(mbase + 8 * g + r) * 1024 + nn] =
                  f2b(acc[i][j][4 * g + r]);
        } else {
          // Vt @ C + 16M elems, transposed [1024][8192]
          ushort* Vo = (ushort*)C + (size_t)16 * MEG;
#pragma unroll
          for (int g = 0; g < 4; ++g) {
            uint lo = (uint)f2b(acc[i][j][4 * g + 0]) |
                      ((uint)f2b(acc[i][j][4 * g + 1]) << 16);
            uint hi = (uint)f2b(acc[i][j][4 * g + 2]) |
                      ((uint)f2b(acc[i][j][4 * g + 3]) << 16);
            *(uint2*)&Vo[(size_t)(ng - 2048) * 8192 + mbase + 8 * g] =
                make_uint2(lo, hi);
          }
        }
      }
  } else if constexpr (MODE == 1) {   // p = exp2(s*scale), row sums -> Lsum
    ushort* Cb = (ushort*)C + (size_t)bz * sC;
    float* Lb = Lsum + (size_t)bz * 2048;
    const int ng0 = n0 + nw * (BN / 2) + l32;
#pragma unroll
    for (int i = 0; i < 2; ++i) {
      const int mbase = m0 + mw * 64 + i * 32 + 4 * lh;
#pragma unroll
      for (int g = 0; g < 4; ++g)
#pragma unroll
        for (int r = 0; r < 4; ++r) {
          const int mg = mbase + 8 * g + r;
          float p0 = exp2f(acc[i][0][4 * g + r] * scale);
          float p1 = exp2f(acc[i][NJ - 1][4 * g + r] * scale);
          ushort u0 = f2b(p0), u1 = f2b(p1);
          Cb[(size_t)mg * ldc + ng0]      = u0;
          Cb[(size_t)mg * ldc + ng0 + 32] = u1;
          float ps = b2f(u0) + b2f(u1);   // sum of *rounded* p (matches PV)
#pragma unroll
          for (int d = 1; d < 32; d <<= 1) ps += __shfl_xor(ps, d);
          if (l32 == 0) atomicAdd(&Lb[mg], ps);
        }
    }
  } else {                    // MODE 2: normalized fp32 output
    float* Cb = (float*)C + (size_t)bz * sC;
    const float* Lb = Lsum + (size_t)bz * 2048;
#pragma unroll
    for (int i = 0; i < 2; ++i) {
      const int mbase = m0 + mw * 64 + i * 32 + 4 * lh;
#pragma unroll
      for (int g = 0; g < 4; ++g)
#pragma unroll
        for (int r = 0; r < 4; ++r) {
          const int mg = mbase + 8 * g + r;
          const float inv = 1.0f / Lb[mg];
#pragma unroll
          for (int j = 0; j < NJ; ++j) {
            const int ng = n0 + nw * (BN / 2) + j * 32 + l32;
            Cb[(size_t)mg * ldc + ng] = acc[i][j][4 * g + r] * inv;
          }
        }
    }
  }
}

// ---- distinct symbols per stage (counter attribution) ----
__global__ __launch_bounds__(256, 3) void gemm_qkv(
    const ushort* __restrict__ A, int lda, size_t sA,
    const ushort* __restrict__ B, int ldb, size_t sB,
    void* __restrict__ C, int ldc, size_t sC, int K, float scale,
    float* __restrict__ Lsum) {
  gemm_core<0, 128>(A, lda, sA, B, ldb, sB, C, ldc, sC, K, scale, Lsum);
}
__global__ __launch_bounds__(256, 3) void gemm_s(
    const ushort* __restrict__ A, int lda, size_t sA,
    const ushort* __restrict__ B, int ldb, size_t sB,
    void* __restrict__ C, int ldc, size_t sC, int K, float scale,
    float* __restrict__ Lsum) {
  gemm_core<1, 128>(A, lda, sA, B, ldb, sB, C, ldc, sC, K, scale, Lsum);
}
__global__ __launch_bounds__(256, 3) void gemm_pv(
    const ushort* __restrict__ A, int lda, size_t sA,
    const ushort* __restrict__ B, int ldb, size_t sB,
    void* __restrict__ C, int ldc, size_t sC, int K, float scale,
    float* __restrict__ Lsum) {
  gemm_core<2, 128>(A, lda, sA, B, ldb, sB, C, ldc, sC, K, scale, Lsum);
}

// ---------------------------------------------------------------------------
// ws layout (ushort elems), total 80 MiB + 32 KiB  (proven ws >= 90.2 MB):
//   Qb @ 0      [8192][1024]   (16 MiB)
//   Kb @ 8M     [8192][1024]   (16 MiB)
//   Vt @ 16M    [1024][8192]   (16 MiB)
//   xb @ 24M    [8192][1024]   (16 MiB)  -- dead after QKV
//   Wb @ 32M    [3072][1024]   ( 6 MiB)  -- dead after QKV
//   P  @ 24M    [4][2048][2048] (32 MiB) -- OVERLAYS xb+Wb (both dead)
//   Ls @ 40M    fp32 [4][2048]  (32 KiB)
// ---------------------------------------------------------------------------
extern "C" void kernel_launch(void* const* d_in, const int* in_sizes, int n_in,
                              void* d_out, int out_size, void* d_ws, size_t ws_size,
                              hipStream_t stream) {
  const float* x  = (const float*)d_in[0];
  const float* Wq = (const float*)d_in[1];
  const float* Wk = (const float*)d_in[2];
  const float* Wv = (const float*)d_in[3];
  float* outp = (float*)d_out;

  const float SCALE = 1.4426950408889634f / 32.0f;   // log2(e)/sqrt(1024)

  ushort* W0 = (ushort*)d_ws;
  ushort* Qb = W0;
  ushort* Kb = W0 + (size_t)8 * MEG;
  ushort* Vt = W0 + (size_t)16 * MEG;
  ushort* xb = W0 + (size_t)24 * MEG;
  ushort* Wb = W0 + (size_t)32 * MEG;
  ushort* Pb = W0 + (size_t)24 * MEG;            // overlays xb/Wb after QKV

  const size_t NEED_FULL = ((size_t)40 * MEG) * 2 + 4 * 2048 * 4;  // 83,918,848
  const bool full = ws_size >= NEED_FULL;
  float* Ls = full ? (float*)(W0 + (size_t)40 * MEG)
                   : (float*)(W0 + (size_t)28 * MEG);  // per-batch: P is 8 MiB

  cvt_all<<<5633, 256, 0, stream>>>(x, Wq, Wk, Wv, xb, Wb, Ls);

  // fused QKV projection: [8192x1024] x [3072x1024]^T, split epilogue
  gemm_qkv<<<dim3(24, 64, 1), 256, 0, stream>>>(
      xb, 1024, 0, Wb, 1024, 0, Qb, 1024, 0, 1024, 1.f, nullptr);

  if (full) {
    gemm_s<<<dim3(16, 16, 4), 256, 0, stream>>>(
        Qb, 1024, (size_t)2048 * 1024, Kb, 1024, (size_t)2048 * 1024,
        Pb, 2048, (size_t)2048 * 2048, 1024, SCALE, Ls);
    gemm_pv<<<dim3(8, 16, 4), 256, 0, stream>>>(
        Pb, 2048, (size_t)2048 * 2048, Vt, 8192, 2048,
        outp, 1024, (size_t)2048 * 1024, 2048, 1.f, Ls);
  } else {
    // per-batch fallback (P single batch @24M, Ls @28M)
    for (int b = 0; b < 4; ++b) {
      (void)hipMemsetAsync(Ls, 0, 2048 * sizeof(float), stream);
      gemm_s<<<dim3(16, 16, 1), 256, 0, stream>>>(
          Qb + (size_t)b * 2048 * 1024, 1024, 0,
          Kb + (size_t)b * 2048 * 1024, 1024, 0,
          Pb, 2048, 0, 1024, SCALE, Ls);
      gemm_pv<<<dim3(8, 16, 1), 256, 0, stream>>>(
          Pb, 2048, 0, Vt + (size_t)b * 2048, 8192, 0,
          outp + (size_t)b * 2048 * 1024, 1024, 0, 2048, 1.f, Ls);
    }
  }
}

// Round 12
// 248.183 us; speedup vs baseline: 1.0698x; 1.0097x over previous
//
#include <hip/hip_runtime.h>
#include <stdint.h>

typedef unsigned int uint;
typedef unsigned short ushort;
typedef __attribute__((ext_vector_type(8))) short short8;
typedef __attribute__((ext_vector_type(16))) float floatx16;

#define MEG (1024u * 1024u)

// ---------- helpers ----------
__device__ inline ushort f2b(float f) {           // fp32 -> bf16 RNE
  union { float f; uint u; } c; c.f = f;
  uint u = c.u;
  u = (u + 0x7fffu + ((u >> 16) & 1u)) >> 16;
  return (ushort)u;
}
__device__ inline float b2f(ushort u) {
  union { uint i; float f; } c; c.i = ((uint)u) << 16; return c.f;
}

__device__ inline void gl_lds16(const ushort* g, ushort* l) {
  // async global->LDS, 16B/lane; LDS dest = wave-uniform base + lane*16
  __builtin_amdgcn_global_load_lds(
      (const __attribute__((address_space(1))) void*)g,
      (__attribute__((address_space(3))) void*)l, 16, 0, 0);
}

// ---------------------------------------------------------------------------
// fp32->bf16 convert (x: 4096 blocks, W: 3x512 blocks) + Ls zeroing (1 block).
// ---------------------------------------------------------------------------
__global__ __launch_bounds__(256) void cvt_all(
    const float* __restrict__ x,  const float* __restrict__ wq,
    const float* __restrict__ wk, const float* __restrict__ wv,
    ushort* __restrict__ xb, ushort* __restrict__ wb,
    float* __restrict__ ls)
{
  const int b = blockIdx.x;
  if (b >= 5632) {                      // zero Lsum[4][2048]
    float4 z = make_float4(0.f, 0.f, 0.f, 0.f);
#pragma unroll
    for (int j = 0; j < 8; ++j)
      ((float4*)ls)[threadIdx.x * 8 + j] = z;
    return;
  }
  const float* s; ushort* d; int i;
  if (b < 4096) {
    s = x; d = xb; i = b * 256 + threadIdx.x;
  } else {
    int t = b - 4096;
    int wsel = t >> 9;
    s = (wsel == 0) ? wq : (wsel == 1) ? wk : wv;
    d = wb + (size_t)wsel * MEG;
    i = (t & 511) * 256 + threadIdx.x;
  }
  float4 a = ((const float4*)s)[i * 2];
  float4 c = ((const float4*)s)[i * 2 + 1];
  short8 v;
  v[0] = (short)f2b(a.x); v[1] = (short)f2b(a.y);
  v[2] = (short)f2b(a.z); v[3] = (short)f2b(a.w);
  v[4] = (short)f2b(c.x); v[5] = (short)f2b(c.y);
  v[6] = (short)f2b(c.z); v[7] = (short)f2b(c.w);
  ((short8*)d)[i] = v;
}

// ---------------------------------------------------------------------------
// Shared GEMM-BT core:  C[m][n] = f( sum_k A[m][k] * B[n][k] )
// 128 x BN block tile, BK=64, 256 thr = 2x2 waves, MFMA 32x32x16
// (floatx16 acc), global_load_lds width-16 staging into XOR-swizzled
// [rows][64] LDS tiles (chunk' = chunk ^ ((r^(r>>3))&7)) — kills all LDS
// bank conflicts (R5: 6.3M -> 0). No XCD swizzle (R6 regressed).
// MODE 0 (BN=128): fused-QKV split (n<2048 -> Q/K bf16 row-major, else Vt^T)
// MODE 1 (BN=128): p = exp2(s*scale) bf16 out; row sums atomically into Lsum
//                  (no max subtraction: |s|*scale bounded ~8, fp32-safe)
// MODE 2: fp32 out, multiplied by 1/Lsum[row]
// ---------------------------------------------------------------------------
template <int MODE, int BN>
__device__ __forceinline__ void gemm_core(
    const ushort* __restrict__ A, int lda, size_t sA,
    const ushort* __restrict__ B, int ldb, size_t sB,
    void* __restrict__ C, int ldc, size_t sC,
    int K, float scale, float* __restrict__ Lsum)
{
  constexpr int NJ = BN / 64;          // n-frags per wave (2 or 1)
  constexpr int NB = BN / 32;          // 32-row staging groups for B (4 or 2)
  __shared__ ushort As[128 * 64];
  __shared__ ushort Bs[BN * 64];

  const int tid = threadIdx.x;
  const int bz  = blockIdx.z;
  A += (size_t)bz * sA;
  B += (size_t)bz * sB;

  const int m0 = blockIdx.y * 128;
  const int n0 = blockIdx.x * BN;

  const int lane = tid & 63;
  const int w    = tid >> 6;
  const int l32  = lane & 31;
  const int lh   = lane >> 5;          // 0/1 -> k-half of the 16-k step
  const int mw   = w >> 1;
  const int nw   = w & 1;

  // ---- staging pointers (32 rows per group; 8 lanes per 128B row) ----
  const int srow = tid >> 3;
  const ushort* agp[4];
  const ushort* bgp[NB];
#pragma unroll
  for (int c4 = 0; c4 < 4; ++c4) {
    int r   = c4 * 32 + srow;
    int col = (((tid & 7) ^ ((r ^ (r >> 3)) & 7))) * 8;
    agp[c4] = A + (size_t)(m0 + r) * lda + col;
  }
#pragma unroll
  for (int cb = 0; cb < NB; ++cb) {
    int r   = cb * 32 + srow;
    int col = (((tid & 7) ^ ((r ^ (r >> 3)) & 7))) * 8;
    bgp[cb] = B + (size_t)(n0 + r) * ldb + col;
  }

  // ---- fragment rows + swizzle keys (loop-invariant) ----
  int arow[2], aswz[2], brow[NJ], bswz[NJ];
#pragma unroll
  for (int t = 0; t < 2; ++t) {
    arow[t] = mw * 64 + t * 32 + l32;
    aswz[t] = (arow[t] ^ (arow[t] >> 3)) & 7;
  }
#pragma unroll
  for (int t = 0; t < NJ; ++t) {
    brow[t] = nw * (BN / 2) + t * 32 + l32;
    bswz[t] = (brow[t] ^ (brow[t] >> 3)) & 7;
  }

  floatx16 acc[2][NJ];
#pragma unroll
  for (int i = 0; i < 2; ++i)
#pragma unroll
    for (int j = 0; j < NJ; ++j)
#pragma unroll
      for (int r = 0; r < 16; ++r) acc[i][j][r] = 0.f;

  for (int k0 = 0; k0 < K; k0 += 64) {
    __syncthreads();
#pragma unroll
    for (int c4 = 0; c4 < 4; ++c4) {
      gl_lds16(agp[c4], &As[(c4 * 32 + w * 8) * 64]);
      agp[c4] += 64;
    }
#pragma unroll
    for (int cb = 0; cb < NB; ++cb) {
      gl_lds16(bgp[cb], &Bs[(cb * 32 + w * 8) * 64]);
      bgp[cb] += 64;
    }
    __syncthreads();

#pragma unroll
    for (int s = 0; s < 4; ++s) {        // 4 k-steps of 16
      short8 af[2], bf[NJ];
#pragma unroll
      for (int t = 0; t < 2; ++t)
        af[t] = *(const short8*)&As[arow[t] * 64 + (((s * 2 + lh) ^ aswz[t]) * 8)];
#pragma unroll
      for (int t = 0; t < NJ; ++t)
        bf[t] = *(const short8*)&Bs[brow[t] * 64 + (((s * 2 + lh) ^ bswz[t]) * 8)];
#pragma unroll
      for (int i = 0; i < 2; ++i)
#pragma unroll
        for (int j = 0; j < NJ; ++j)
          acc[i][j] = __builtin_amdgcn_mfma_f32_32x32x16_bf16(
              af[i], bf[j], acc[i][j], 0, 0, 0);
    }
  }

  // ---- epilogue; C/D (32x32): col = lane&31, row = (reg&3)+8*(reg>>2)+4*lh
  if constexpr (MODE == 0) {   // fused-QKV split
#pragma unroll
    for (int i = 0; i < 2; ++i)
#pragma unroll
      for (int j = 0; j < NJ; ++j) {
        const int mbase = m0 + mw * 64 + i * 32 + 4 * lh;
        const int ng    = n0 + nw * (BN / 2) + j * 32 + l32;
        if (ng < 2048) {
          // Qb @ C, Kb @ C + 8M elems
          ushort* dst = (ushort*)C + (size_t)(ng >> 10) * (8u * MEG);
          const int nn = ng & 1023;
#pragma unroll
          for (int g = 0; g < 4; ++g)
#pragma unroll
            for (int r = 0; r < 4; ++r)
              dst[(size_t)(mbase + 8 * g + r) * 1024 + nn] =
                  f2b(acc[i][j][4 * g + r]);
        } else {
          // Vt @ C + 16M elems, transposed [1024][8192]
          ushort* Vo = (ushort*)C + (size_t)16 * MEG;
#pragma unroll
          for (int g = 0; g < 4; ++g) {
            uint lo = (uint)f2b(acc[i][j][4 * g + 0]) |
                      ((uint)f2b(acc[i][j][4 * g + 1]) << 16);
            uint hi = (uint)f2b(acc[i][j][4 * g + 2]) |
                      ((uint)f2b(acc[i][j][4 * g + 3]) << 16);
            *(uint2*)&Vo[(size_t)(ng - 2048) * 8192 + mbase + 8 * g] =
                make_uint2(lo, hi);
          }
        }
      }
  } else if constexpr (MODE == 1) {   // p = exp2(s*scale), row sums -> Lsum
    ushort* Cb = (ushort*)C + (size_t)bz * sC;
    float* Lb = Lsum + (size_t)bz * 2048;
    const int ng0 = n0 + nw * (BN / 2) + l32;
#pragma unroll
    for (int i = 0; i < 2; ++i) {
      const int mbase = m0 + mw * 64 + i * 32 + 4 * lh;
#pragma unroll
      for (int g = 0; g < 4; ++g)
#pragma unroll
        for (int r = 0; r < 4; ++r) {
          const int mg = mbase + 8 * g + r;
          float p0 = exp2f(acc[i][0][4 * g + r] * scale);
          float p1 = exp2f(acc[i][NJ - 1][4 * g + r] * scale);
          ushort u0 = f2b(p0), u1 = f2b(p1);
          Cb[(size_t)mg * ldc + ng0]      = u0;
          Cb[(size_t)mg * ldc + ng0 + 32] = u1;
          float ps = b2f(u0) + b2f(u1);   // sum of *rounded* p (matches PV)
#pragma unroll
          for (int d = 1; d < 32; d <<= 1) ps += __shfl_xor(ps, d);
          if (l32 == 0) atomicAdd(&Lb[mg], ps);
        }
    }
  } else {                    // MODE 2: normalized fp32 output
    float* Cb = (float*)C + (size_t)bz * sC;
    const float* Lb = Lsum + (size_t)bz * 2048;
#pragma unroll
    for (int i = 0; i < 2; ++i) {
      const int mbase = m0 + mw * 64 + i * 32 + 4 * lh;
#pragma unroll
      for (int g = 0; g < 4; ++g)
#pragma unroll
        for (int r = 0; r < 4; ++r) {
          const int mg = mbase + 8 * g + r;
          const float inv = 1.0f / Lb[mg];
#pragma unroll
          for (int j = 0; j < NJ; ++j) {
            const int ng = n0 + nw * (BN / 2) + j * 32 + l32;
            Cb[(size_t)mg * ldc + ng] = acc[i][j][4 * g + r] * inv;
          }
        }
    }
  }
}

// ---- distinct symbols per stage (counter attribution) ----
__global__ __launch_bounds__(256, 3) void gemm_qkv(
    const ushort* __restrict__ A, int lda, size_t sA,
    const ushort* __restrict__ B, int ldb, size_t sB,
    void* __restrict__ C, int ldc, size_t sC, int K, float scale,
    float* __restrict__ Lsum) {
  gemm_core<0, 128>(A, lda, sA, B, ldb, sB, C, ldc, sC, K, scale, Lsum);
}
// (256,4): S grid is exactly 1024 blocks = 4/CU x 256 CU -> whole dispatch
// resident in one round (fixes the 1.33-round grid quantization; R11 S ran
// at 491 TF vs QKV 718 with identical per-block structure). 64 VGPR + 64
// AGPR = 128 unified regs = the 16-wave/CU boundary (m69) -> should fit.
__global__ __launch_bounds__(256, 4) void gemm_s(
    const ushort* __restrict__ A, int lda, size_t sA,
    const ushort* __restrict__ B, int ldb, size_t sB,
    void* __restrict__ C, int ldc, size_t sC, int K, float scale,
    float* __restrict__ Lsum) {
  gemm_core<1, 128>(A, lda, sA, B, ldb, sB, C, ldc, sC, K, scale, Lsum);
}
__global__ __launch_bounds__(256, 3) void gemm_pv(
    const ushort* __restrict__ A, int lda, size_t sA,
    const ushort* __restrict__ B, int ldb, size_t sB,
    void* __restrict__ C, int ldc, size_t sC, int K, float scale,
    float* __restrict__ Lsum) {
  gemm_core<2, 128>(A, lda, sA, B, ldb, sB, C, ldc, sC, K, scale, Lsum);
}

// ---------------------------------------------------------------------------
// ws layout (ushort elems), total 80 MiB + 32 KiB  (proven ws >= 90.2 MB):
//   Qb @ 0      [8192][1024]   (16 MiB)
//   Kb @ 8M     [8192][1024]   (16 MiB)
//   Vt @ 16M    [1024][8192]   (16 MiB)
//   xb @ 24M    [8192][1024]   (16 MiB)  -- dead after QKV
//   Wb @ 32M    [3072][1024]   ( 6 MiB)  -- dead after QKV
//   P  @ 24M    [4][2048][2048] (32 MiB) -- OVERLAYS xb+Wb (both dead)
//   Ls @ 40M    fp32 [4][2048]  (32 KiB)
// ---------------------------------------------------------------------------
extern "C" void kernel_launch(void* const* d_in, const int* in_sizes, int n_in,
                              void* d_out, int out_size, void* d_ws, size_t ws_size,
                              hipStream_t stream) {
  const float* x  = (const float*)d_in[0];
  const float* Wq = (const float*)d_in[1];
  const float* Wk = (const float*)d_in[2];
  const float* Wv = (const float*)d_in[3];
  float* outp = (float*)d_out;

  const float SCALE = 1.4426950408889634f / 32.0f;   // log2(e)/sqrt(1024)

  ushort* W0 = (ushort*)d_ws;
  ushort* Qb = W0;
  ushort* Kb = W0 + (size_t)8 * MEG;
  ushort* Vt = W0 + (size_t)16 * MEG;
  ushort* xb = W0 + (size_t)24 * MEG;
  ushort* Wb = W0 + (size_t)32 * MEG;
  ushort* Pb = W0 + (size_t)24 * MEG;            // overlays xb/Wb after QKV

  const size_t NEED_FULL = ((size_t)40 * MEG) * 2 + 4 * 2048 * 4;  // 83,918,848
  const bool full = ws_size >= NEED_FULL;
  float* Ls = full ? (float*)(W0 + (size_t)40 * MEG)
                   : (float*)(W0 + (size_t)28 * MEG);  // per-batch: P is 8 MiB

  cvt_all<<<5633, 256, 0, stream>>>(x, Wq, Wk, Wv, xb, Wb, Ls);

  // fused QKV projection: [8192x1024] x [3072x1024]^T, split epilogue
  gemm_qkv<<<dim3(24, 64, 1), 256, 0, stream>>>(
      xb, 1024, 0, Wb, 1024, 0, Qb, 1024, 0, 1024, 1.f, nullptr);

  if (full) {
    gemm_s<<<dim3(16, 16, 4), 256, 0, stream>>>(
        Qb, 1024, (size_t)2048 * 1024, Kb, 1024, (size_t)2048 * 1024,
        Pb, 2048, (size_t)2048 * 2048, 1024, SCALE, Ls);
    gemm_pv<<<dim3(8, 16, 4), 256, 0, stream>>>(
        Pb, 2048, (size_t)2048 * 2048, Vt, 8192, 2048,
        outp, 1024, (size_t)2048 * 1024, 2048, 1.f, Ls);
  } else {
    // per-batch fallback (P single batch @24M, Ls @28M)
    for (int b = 0; b < 4; ++b) {
      (void)hipMemsetAsync(Ls, 0, 2048 * sizeof(float), stream);
      gemm_s<<<dim3(16, 16, 1), 256, 0, stream>>>(
          Qb + (size_t)b * 2048 * 1024, 1024, 0,
          Kb + (size_t)b * 2048 * 1024, 1024, 0,
          Pb, 2048, 0, 1024, SCALE, Ls);
      gemm_pv<<<dim3(8, 16, 1), 256, 0, stream>>>(
          Pb, 2048, 0, Vt + (size_t)b * 2048, 8192, 0,
          outp + (size_t)b * 2048 * 1024, 1024, 0, 2048, 1.f, Ls);
    }
  }
}